// Round 15
// baseline (439.442 us; speedup 1.0000x reference)
//
#include <hip/hip_runtime.h>
#include <hip/hip_bf16.h>
#include <cstdint>
#include <cstddef>

#define HDIM 4096
#define MROWS 8192
#define LN_EPS 1e-5f

typedef __bf16 bf16_t;
typedef __bf16 bf16x4_t __attribute__((ext_vector_type(4)));
typedef __bf16 bf16x8_t __attribute__((ext_vector_type(8)));
typedef float f32x4_t __attribute__((ext_vector_type(4)));

typedef const __attribute__((address_space(1))) void gvoid_t;
typedef __attribute__((address_space(3))) void lvoid_t;

__device__ __forceinline__ float softplus_f(float x) {
    return fmaxf(x, 0.f) + log1pf(expf(-fabsf(x)));
}

// ---- W = mu + softplus(rho)*eps  -> bf16 ----
__global__ __launch_bounds__(256) void wgen_kernel(
    const float* __restrict__ mu, const float* __restrict__ rho,
    const float* __restrict__ eps, bf16_t* __restrict__ W)
{
    int i = (blockIdx.x * 256 + threadIdx.x) * 4;
    float4 m = *(const float4*)(mu + i);
    float4 r = *(const float4*)(rho + i);
    float4 e = *(const float4*)(eps + i);
    bf16x4_t o;
    o[0] = (bf16_t)(m.x + softplus_f(r.x) * e.x);
    o[1] = (bf16_t)(m.y + softplus_f(r.y) * e.y);
    o[2] = (bf16_t)(m.z + softplus_f(r.z) * e.z);
    o[3] = (bf16_t)(m.w + softplus_f(r.w) * e.w);
    *(bf16x4_t*)(W + i) = o;
}

// ---- bias = b_mu + softplus(b_rho)*eps_b  (fp32) ----
__global__ __launch_bounds__(256) void biasgen_kernel(
    const float* __restrict__ mu, const float* __restrict__ rho,
    const float* __restrict__ eps, float* __restrict__ b)
{
    int i = blockIdx.x * 256 + threadIdx.x;
    b[i] = mu[i] + softplus_f(rho[i]) * eps[i];
}

// ---- LayerNorm per row of 4096, fp32 in -> bf16 out ----
__global__ __launch_bounds__(256) void ln_kernel(
    const float* __restrict__ x, const float* __restrict__ gamma,
    const float* __restrict__ beta, bf16_t* __restrict__ h)
{
    int row = blockIdx.x;
    const float* xr = x + (size_t)row * HDIM;
    int t = threadIdx.x;
    float4 v[4];
    float s = 0.f, s2 = 0.f;
#pragma unroll
    for (int j = 0; j < 4; ++j) {
        v[j] = *(const float4*)(xr + j * 1024 + t * 4);
        s  += v[j].x + v[j].y + v[j].z + v[j].w;
        s2 += v[j].x * v[j].x + v[j].y * v[j].y + v[j].z * v[j].z + v[j].w * v[j].w;
    }
#pragma unroll
    for (int off = 32; off > 0; off >>= 1) {
        s  += __shfl_down(s, off);
        s2 += __shfl_down(s2, off);
    }
    __shared__ float ps[4], ps2[4];
    if ((t & 63) == 0) { ps[t >> 6] = s; ps2[t >> 6] = s2; }
    __syncthreads();
    float tot  = ps[0] + ps[1] + ps[2] + ps[3];
    float tot2 = ps2[0] + ps2[1] + ps2[2] + ps2[3];
    float mean = tot * (1.f / HDIM);
    float var  = tot2 * (1.f / HDIM) - mean * mean;
    float rstd = rsqrtf(var + LN_EPS);
    bf16_t* hr = h + (size_t)row * HDIM;
#pragma unroll
    for (int j = 0; j < 4; ++j) {
        int c = j * 1024 + t * 4;
        float4 g  = *(const float4*)(gamma + c);
        float4 bb = *(const float4*)(beta + c);
        bf16x4_t o;
        o[0] = (bf16_t)((v[j].x - mean) * rstd * g.x + bb.x);
        o[1] = (bf16_t)((v[j].y - mean) * rstd * g.y + bb.y);
        o[2] = (bf16_t)((v[j].z - mean) * rstd * g.z + bb.z);
        o[3] = (bf16_t)((v[j].w - mean) * rstd * g.w + bb.w);
        *(bf16x4_t*)(hr + c) = o;
    }
}

__device__ __forceinline__ void gload_lds16(const bf16_t* g, const char* l) {
    __builtin_amdgcn_global_load_lds((gvoid_t*)g, (lvoid_t*)l, 16, 0, 0);
}

// st-style LDS swizzle: flip byte bits 4,5 with bits 7,8. Involution,
// confined to 512B blocks.
__device__ __forceinline__ int swz(int x) { return x ^ ((x >> 3) & 0x30); }

// ---- GEMM: out[m][o] = x[m][o] + gelu( sum_k h[m][k]*W[o][k] + bias[o] ) ----
// r7 skeleton (256x256, BK=32, 8 waves 2Mx4N, ring-4, 16x16x32 MFMA,
// vmcnt(4)+1 barrier/K-tile) + FULL fragment double-buffering:
// iteration t reads ALL 12 fragments of tile t+1 and MFMAs tile t's set
// (read one full K-tile ago). lgkm(12) before the MFMAs is the exact FIFO
// wait: drains the consumed (oldest) set, keeps the 12 new reads in flight
// -> zero read-latency exposure (old set is ~2700 cyc old).
//
// VGPR trick: post-swizzle read offsets are LINEAR in fragment index
// (m*1024 touches only bits >=10; swz maps bits 7,8 -> 4,5), so
// swz(base + m*1024) = swz(base) + m*1024 -> 2 base VGPRs + ds_read
// offset: immediates replace 12 offset VGPRs. 2 sets x 12 x bf16x8 = 96
// VGPR + 128 acc + ~25 addr ~= 249 < 256 (no spill).
//
// Ledger (delta from r7's proven one):
//  RAW(read):  RDALL(t+1) at iter t reads buf[(t+1)&3]; tile t+1 staged at
//    t-2, drained by vmcnt(4) at end of t-1, published by t-1's barrier ✓.
//  RAW(reg):   MFMA(set read at t-1) gated by lgkm(12) (FIFO: drains all
//    older ds ops) ✓.
//  WAR(stage): stages at t write buf[(t+3)&3]=buf[(t-1)&3]; reads OF tile
//    t-1 (issued t-2) drained by t-1's lgkm(12) before its exit barrier ✓.
//  vmcnt(4): outstanding at end of t = tile t+2's 4 + tile t+3's 4; drains
//    t+2 (read at t+1 after barrier), keeps t+3 ✓.  Prologue: tiles 0,1,2
//    staged; vmcnt(4) keeps tile 2 (drained by end-of-0's vmcnt) ✓.
__global__ __launch_bounds__(512, 2) void gemm_kernel(
    const bf16_t* __restrict__ A,   // [8192][4096] h (bf16)
    const bf16_t* __restrict__ B,   // [4096][4096] W (bf16, row=o col=k)
    const float* __restrict__ bias, // [4096]
    const float* __restrict__ xres, // [8192][4096] residual fp32
    float* __restrict__ out)        // [8192][4096]
{
    __shared__ char lds[131072];    // ring: buf b at b*32768; A at +0, B at +16KB

    const int tid  = threadIdx.x;
    const int lane = tid & 63, w = tid >> 6;
    const int g = lane >> 4, fr = lane & 15;
    const int wm = w >> 2, wn = w & 3;   // wave grid 2(M) x 4(N)

    // T1: bijective XCD swizzle (512 blocks, 512%8==0)
    int bid = blockIdx.x;
    int wg  = (bid & 7) * 64 + (bid >> 3);
    const int tileN = (wg & 15) * 256;
    const int tileM = (wg >> 4) * 256;

    // staging: linear LDS dest D = r*8192 + w*1024 + lane*16 per region;
    // LDS[D] holds linear-image value at S = swz(D).
    const bf16_t* srcA[2];
    const bf16_t* srcB[2];
    int ldstA[2], ldstB[2];
#pragma unroll
    for (int r = 0; r < 2; ++r) {
        int D = r * 8192 + w * 1024 + lane * 16;
        int S = swz(D);
        int row = S >> 6, colel = (S & 63) >> 1;
        srcA[r] = A + (size_t)(tileM + row) * HDIM + colel;
        srcB[r] = B + (size_t)(tileN + row) * HDIM + colel;
        ldstA[r] = r * 8192 + w * 1024;
        ldstB[r] = 16384 + r * 8192 + w * 1024;
    }

    // base read offsets (fragment index folds into ds_read offset: imm)
    const int aoff0 = swz(wm * 8192 + fr * 64 + g * 16);
    const int boff0 = 16384 + swz(wn * 4096 + fr * 64 + g * 16);

    f32x4_t acc[8][4] = {};
    const int NT = HDIM / 32;  // 128 K-tiles

    // two full fragment sets (8 A + 4 B each)
    bf16x8_t sa0, sa1, sa2, sa3, sa4, sa5, sa6, sa7, sv0, sv1, sv2, sv3;
    bf16x8_t ta0, ta1, ta2, ta3, ta4, ta5, ta6, ta7, tv0, tv1, tv2, tv3;

#define STAGE_A(bb, kofs)                                        \
    do {                                                         \
        gload_lds16(srcA[0] + (kofs), &lds[(bb) + ldstA[0]]);    \
        gload_lds16(srcA[1] + (kofs), &lds[(bb) + ldstA[1]]);    \
    } while (0)
#define STAGE_B(bb, kofs)                                        \
    do {                                                         \
        gload_lds16(srcB[0] + (kofs), &lds[(bb) + ldstB[0]]);    \
        gload_lds16(srcB[1] + (kofs), &lds[(bb) + ldstB[1]]);    \
    } while (0)
#define CL(AF, V, R)                                                            \
    acc[R][0] = __builtin_amdgcn_mfma_f32_16x16x32_bf16(AF, V##0, acc[R][0], 0, 0, 0); \
    acc[R][1] = __builtin_amdgcn_mfma_f32_16x16x32_bf16(AF, V##1, acc[R][1], 0, 0, 0); \
    acc[R][2] = __builtin_amdgcn_mfma_f32_16x16x32_bf16(AF, V##2, acc[R][2], 0, 0, 0); \
    acc[R][3] = __builtin_amdgcn_mfma_f32_16x16x32_bf16(AF, V##3, acc[R][3], 0, 0, 0);
#define SCHEDB __builtin_amdgcn_sched_barrier(0)
#define LGKM(n) do { asm volatile("s_waitcnt lgkmcnt(" #n ")" ::: "memory"); SCHEDB; } while (0)

    // ds_read_b128 with compile-time offset immediate (f32x4 out, bitcast)
#define DSR(dst, base, imm)                                              \
    { f32x4_t r_;                                                        \
      asm volatile("ds_read_b128 %0, %1 offset:" #imm                    \
                   : "=v"(r_) : "v"((lvoid_t*)(base)));                  \
      dst = __builtin_bit_cast(bf16x8_t, r_); }

    // RDALL: all 12 fragment reads of tile tc into set (SA, SV)
#define RDALL(tc, SA, SV)                                                \
    do { const char* bp_ = &lds[((tc) & 3) * 32768];                     \
        const char* ba_ = bp_ + aoff0;                                   \
        const char* bb_ = bp_ + boff0;                                   \
        DSR(SV##0, bb_, 0)    DSR(SV##1, bb_, 1024)                      \
        DSR(SV##2, bb_, 2048) DSR(SV##3, bb_, 3072)                      \
        DSR(SA##0, ba_, 0)    DSR(SA##1, ba_, 1024)                      \
        DSR(SA##2, ba_, 2048) DSR(SA##3, ba_, 3072)                      \
        DSR(SA##4, ba_, 4096) DSR(SA##5, ba_, 5120)                      \
        DSR(SA##6, ba_, 6144) DSR(SA##7, ba_, 7168) } while (0)

    // One K-tile: read ALL of tile t+1 into (NA,NV); MFMA on (CA,CV).
#define KTILE(tc, CA, CV, NA, NV)                                     \
    do {                                                              \
        const int sb_ = (((tc) + 3) & 3) * 32768;                     \
        const int sk_ = (((tc) + 3) & (NT - 1)) * 32;                 \
        RDALL((tc) + 1, NA, NV);                                      \
        STAGE_A(sb_, sk_);                                            \
        STAGE_B(sb_, sk_);                                            \
        SCHEDB;                                                       \
        LGKM(12);  /* FIFO: drains (CA,CV)'s reads, keeps the 12 new */ \
        __builtin_amdgcn_s_setprio(1);                                \
        CL(CA##0, CV, 0) CL(CA##1, CV, 1) CL(CA##2, CV, 2) CL(CA##3, CV, 3) \
        CL(CA##4, CV, 4) CL(CA##5, CV, 5) CL(CA##6, CV, 6) CL(CA##7, CV, 7) \
        __builtin_amdgcn_s_setprio(0);                                \
        SCHEDB;                                                       \
        asm volatile("s_waitcnt vmcnt(4)" ::: "memory");              \
        __builtin_amdgcn_s_barrier();                                 \
        SCHEDB;                                                       \
    } while (0)

    // prologue: stage tiles 0,1,2; drain tiles 0,1 (keep tile 2's 4)
    STAGE_A(0, 0);      STAGE_B(0, 0);
    STAGE_A(32768, 32); STAGE_B(32768, 32);
    STAGE_A(65536, 64); STAGE_B(65536, 64);
    asm volatile("s_waitcnt vmcnt(4)" ::: "memory");
    __builtin_amdgcn_s_barrier();
    SCHEDB;
    RDALL(0, sa, sv);   // set S = tile 0 (12 ds outstanding at loop entry)
    SCHEDB;

#pragma unroll 1
    for (int t = 0; t < NT; t += 2) {
        KTILE(t,     sa, sv, ta, tv);   // even: consume S, read T=tile t+1
        KTILE(t + 1, ta, tv, sa, sv);   // odd:  consume T, read S=tile t+2
    }
#undef KTILE
#undef RDALL
#undef DSR
#undef STAGE_A
#undef STAGE_B

    // epilogue: bias + exact GELU + residual, fp32 out
    // C/D layout: col = lane&15, row = (lane>>4)*4 + j
    const int col0 = tileN + wn * 64 + fr;
    const int row0 = tileM + wm * 128 + g * 4;
#pragma unroll
    for (int n = 0; n < 4; ++n) {
        float bvv = bias[col0 + n * 16];
#pragma unroll
        for (int m = 0; m < 8; ++m) {
#pragma unroll
            for (int j = 0; j < 4; ++j) {
                size_t idx = (size_t)(row0 + m * 16 + j) * HDIM + (col0 + n * 16);
                float v = acc[m][n][j] + bvv;
                float ge = 0.5f * v * (1.0f + erff(v * 0.70710678118654752f));
                out[idx] = xres[idx] + ge;
            }
        }
    }
}

extern "C" void kernel_launch(void* const* d_in, const int* in_sizes, int n_in,
                              void* d_out, int out_size, void* d_ws, size_t ws_size,
                              hipStream_t stream) {
    const float* x        = (const float*)d_in[0];
    const float* ln_gamma = (const float*)d_in[1];
    const float* ln_beta  = (const float*)d_in[2];
    const float* w_mu     = (const float*)d_in[3];
    const float* w_rho    = (const float*)d_in[4];
    const float* b_mu     = (const float*)d_in[5];
    const float* b_rho    = (const float*)d_in[6];
    const float* eps_w    = (const float*)d_in[7];
    const float* eps_b    = (const float*)d_in[8];
    float* out = (float*)d_out;

    char* ws = (char*)d_ws;
    bf16_t* h_bf16 = (bf16_t*)ws;                              // 64 MiB
    bf16_t* W_bf16 = (bf16_t*)(ws + 67108864);                 // 32 MiB
    float*  bias   = (float*)(ws + 67108864 + 33554432);       // 16 KiB

    wgen_kernel<<<16384, 256, 0, stream>>>(w_mu, w_rho, eps_w, W_bf16);
    biasgen_kernel<<<16, 256, 0, stream>>>(b_mu, b_rho, eps_b, bias);
    ln_kernel<<<MROWS, 256, 0, stream>>>(x, ln_gamma, ln_beta, h_bf16);
    gemm_kernel<<<512, 512, 0, stream>>>(h_bf16, W_bf16, bias, x, out);
}